// Round 6
// baseline (2838.486 us; speedup 1.0000x reference)
//
#include <hip/hip_runtime.h>

#define FD 64           // feature dim D = A = G = 64
#define NSLOPE 0.01f
#define SCAN_BS 1024
#define XP_STRIDE 68    // LDS row stride (words) for x' tile: 16B-aligned, bank-spread

__device__ __forceinline__ float lrelu(float v) { return v > 0.f ? v : NSLOPE * v; }

__device__ __forceinline__ unsigned enc_f32(float f) {
    unsigned u = __float_as_uint(f);
    return (u & 0x80000000u) ? ~u : (u | 0x80000000u);
}
__device__ __forceinline__ float dec_f32(unsigned u) {
    return (u & 0x80000000u) ? __uint_as_float(u & 0x7FFFFFFFu) : __uint_as_float(~u);
}

// ---------------- preprocessing: CSR by dst (every launch) ----------------

__global__ void k_hist(const int* __restrict__ dst, int* __restrict__ deg, int E)
{
    int e = blockIdx.x * blockDim.x + threadIdx.x;
    if (e < E) atomicAdd(&deg[dst[e]], 1);
}

__global__ void k_scan1(const int* __restrict__ deg, int* __restrict__ off,
                        int* __restrict__ bsums, int N)
{
    __shared__ int tmp[SCAN_BS];
    int t = threadIdx.x, b = blockIdx.x;
    int i = b * SCAN_BS + t;
    int v = (i < N) ? deg[i] : 0;
    tmp[t] = v;
    __syncthreads();
    for (int d = 1; d < SCAN_BS; d <<= 1) {
        int add = (t >= d) ? tmp[t - d] : 0;
        __syncthreads();
        tmp[t] += add;
        __syncthreads();
    }
    if (i < N) off[i] = tmp[t] - v;
    if (t == SCAN_BS - 1) bsums[b] = tmp[t];
}

__global__ void k_scan2(int* __restrict__ bsums, int nb)
{
    __shared__ int tmp[SCAN_BS];
    int t = threadIdx.x;
    int v = (t < nb) ? bsums[t] : 0;
    tmp[t] = v;
    __syncthreads();
    for (int d = 1; d < SCAN_BS; d <<= 1) {
        int add = (t >= d) ? tmp[t - d] : 0;
        __syncthreads();
        tmp[t] += add;
        __syncthreads();
    }
    if (t < nb) bsums[t] = tmp[t] - v;
}

__global__ void k_scan3(int* __restrict__ off, const int* __restrict__ bsums,
                        int* __restrict__ cursor, int N)
{
    int i = blockIdx.x * blockDim.x + threadIdx.x;
    if (i < N) {
        int o = off[i] + bsums[i >> 10];
        off[i] = o;
        cursor[i] = o;
    }
}

__global__ void k_place(const int* __restrict__ src, const int* __restrict__ dst,
                        int* __restrict__ cursor, int* __restrict__ esrc, int E)
{
    int e = blockIdx.x * blockDim.x + threadIdx.x;
    if (e >= E) return;
    int pos = atomicAdd(&cursor[dst[e]], 1);
    esrc[pos] = src[e];
}

// ---------------- per-step kernels ----------------

// K1: p = x @ Wm + bm.  4 threads/node, 16 cols each (TLP: 400k threads).
__global__ void k_proj(const float* __restrict__ x, const float* __restrict__ Wm,
                       const float* __restrict__ bm, float* __restrict__ p, int N)
{
    int t = blockIdx.x * blockDim.x + threadIdx.x;
    int n = t >> 2, j0 = (t & 3) * 16;
    if (n >= N) return;
    const float* xr = x + (size_t)n * FD;
    float acc[16];
#pragma unroll
    for (int c = 0; c < 4; ++c) {
        float4 b = *(const float4*)&bm[j0 + c * 4];
        acc[c * 4 + 0] = b.x; acc[c * 4 + 1] = b.y; acc[c * 4 + 2] = b.z; acc[c * 4 + 3] = b.w;
    }
    for (int kt = 0; kt < 8; ++kt) {
        float4 a = *(const float4*)(xr + kt * 8);
        float4 b = *(const float4*)(xr + kt * 8 + 4);
        float z8[8] = {a.x, a.y, a.z, a.w, b.x, b.y, b.z, b.w};
#pragma unroll
        for (int kk = 0; kk < 8; ++kk) {
            const float* wr = Wm + (kt * 8 + kk) * FD + j0;
#pragma unroll
            for (int c = 0; c < 4; ++c) {
                float4 w = *(const float4*)(wr + c * 4);
                acc[c * 4 + 0] += z8[kk] * w.x; acc[c * 4 + 1] += z8[kk] * w.y;
                acc[c * 4 + 2] += z8[kk] * w.z; acc[c * 4 + 3] += z8[kk] * w.w;
            }
        }
    }
    float* pr = p + (size_t)n * FD + j0;
#pragma unroll
    for (int c = 0; c < 4; ++c)
        *(float4*)(pr + c * 4) = make_float4(acc[c * 4 + 0], acc[c * 4 + 1],
                                             acc[c * 4 + 2], acc[c * 4 + 3]);
}

// K2: agg[n] = lrelu(max over in-edges of p[src]); empty -> 0.  16 thr/node.
__global__ void k_agg(const float4* __restrict__ p4, const int* __restrict__ off,
                      const int* __restrict__ endp, const int* __restrict__ esrc,
                      float4* __restrict__ agg4, int N)
{
    int tid = threadIdx.x;
    int q = tid & 15;
    int n = blockIdx.x * 16 + (tid >> 4);
    if (n >= N) return;
    int j0 = off[n], j1 = endp[n];
    float4 m = make_float4(-__builtin_inff(), -__builtin_inff(),
                           -__builtin_inff(), -__builtin_inff());
    int j = j0;
    for (; j + 1 < j1; j += 2) {
        int s0 = esrc[j], s1 = esrc[j + 1];
        float4 v0 = p4[(size_t)s0 * 16 + q];
        float4 v1 = p4[(size_t)s1 * 16 + q];
        m.x = fmaxf(m.x, v0.x); m.y = fmaxf(m.y, v0.y);
        m.z = fmaxf(m.z, v0.z); m.w = fmaxf(m.w, v0.w);
        m.x = fmaxf(m.x, v1.x); m.y = fmaxf(m.y, v1.y);
        m.z = fmaxf(m.z, v1.z); m.w = fmaxf(m.w, v1.w);
    }
    if (j < j1) {
        int s0 = esrc[j];
        float4 v0 = p4[(size_t)s0 * 16 + q];
        m.x = fmaxf(m.x, v0.x); m.y = fmaxf(m.y, v0.y);
        m.z = fmaxf(m.z, v0.z); m.w = fmaxf(m.w, v0.w);
    }
    float4 o;
    if (j0 == j1) o = make_float4(0.f, 0.f, 0.f, 0.f);
    else { o.x = lrelu(m.x); o.y = lrelu(m.y); o.z = lrelu(m.z); o.w = lrelu(m.w); }
    agg4[(size_t)n * 16 + q] = o;
}

// K3: 4 threads/node, 16 cols each; block = 256 thr = 64 nodes.
// x' = lrelu([x,xg_b,agg] @ Wa + ba) + x ; gate (shfl-reduce) + per-graph max ;
// feat = lrelu(x' @ Wfeat + bfeat) with x' exchanged through LDS.
__global__ void k_node(const float* __restrict__ x_in, float* __restrict__ x_out,
                       const float* __restrict__ xg, const int* __restrict__ batch,
                       const float* __restrict__ agg,
                       const float* __restrict__ Wa, const float* __restrict__ ba,
                       const float* __restrict__ Wgate, const float* __restrict__ bgate,
                       const float* __restrict__ Wfeat, const float* __restrict__ bfeat,
                       float* __restrict__ gate_out, float* __restrict__ feat_out,
                       unsigned* __restrict__ gmax_enc, int N)
{
    __shared__ float Xp[64 * XP_STRIDE];
    __shared__ unsigned lmax[16];
    const int tid = threadIdx.x;
    if (tid < 16) lmax[tid] = 0u;

    const int ln = tid >> 2;                 // local node 0..63
    const int q  = tid & 3;
    const int j0 = q * 16;
    const int n  = blockIdx.x * 64 + ln;
    const int nc = min(n, N - 1);

    const float* xr  = x_in + (size_t)nc * FD;
    const float* xgr = xg + (size_t)batch[nc] * FD;
    const float* ar  = agg + (size_t)nc * FD;

    float acc[16];
#pragma unroll
    for (int c = 0; c < 4; ++c) {
        float4 b = *(const float4*)&ba[j0 + c * 4];
        acc[c * 4 + 0] = b.x; acc[c * 4 + 1] = b.y; acc[c * 4 + 2] = b.z; acc[c * 4 + 3] = b.w;
    }

    // ---- main GEMM: z[192] @ Wa[192x64], this thread's 16 cols ----
    for (int seg = 0; seg < 3; ++seg) {
        const float* srow = (seg == 0) ? xr : (seg == 1) ? xgr : ar;
        for (int kt = 0; kt < 8; ++kt) {
            float4 a = *(const float4*)(srow + kt * 8);
            float4 b = *(const float4*)(srow + kt * 8 + 4);
            float z8[8] = {a.x, a.y, a.z, a.w, b.x, b.y, b.z, b.w};
#pragma unroll
            for (int kk = 0; kk < 8; ++kk) {
                const float* wr = Wa + (size_t)(seg * 64 + kt * 8 + kk) * FD + j0;
#pragma unroll
                for (int c = 0; c < 4; ++c) {
                    float4 w = *(const float4*)(wr + c * 4);
                    acc[c * 4 + 0] += z8[kk] * w.x; acc[c * 4 + 1] += z8[kk] * w.y;
                    acc[c * 4 + 2] += z8[kk] * w.z; acc[c * 4 + 3] += z8[kk] * w.w;
                }
            }
        }
    }

    // ---- epilogue 1: x' = lrelu(acc) + x ; store global + LDS ; gate partial ----
    float gpart = 0.f;
    float* xo = x_out + (size_t)n * FD + j0;
#pragma unroll
    for (int c = 0; c < 4; ++c) {
        float4 xv = *(const float4*)(xr + j0 + c * 4);
        float4 wg = *(const float4*)&Wgate[j0 + c * 4];
        float v0 = lrelu(acc[c * 4 + 0]) + xv.x;
        float v1 = lrelu(acc[c * 4 + 1]) + xv.y;
        float v2 = lrelu(acc[c * 4 + 2]) + xv.z;
        float v3 = lrelu(acc[c * 4 + 3]) + xv.w;
        *(float4*)&Xp[ln * XP_STRIDE + j0 + c * 4] = make_float4(v0, v1, v2, v3);
        if (n < N) *(float4*)(xo + c * 4) = make_float4(v0, v1, v2, v3);
        gpart += v0 * wg.x + v1 * wg.y + v2 * wg.z + v3 * wg.w;
    }
    // reduce gate across the node's 4 adjacent lanes
    gpart += __shfl_xor(gpart, 1);
    gpart += __shfl_xor(gpart, 2);
    if (q == 0 && n < N) {
        float gv = gpart + bgate[0];
        gate_out[n] = gv;
        atomicMax(&lmax[batch[n]], enc_f32(gv));
    }
    __syncthreads();

    // ---- feat GEMM: x'[64] @ Wfeat[64x64], this thread's 16 cols ----
    float acc2[16];
#pragma unroll
    for (int c = 0; c < 4; ++c) {
        float4 b = *(const float4*)&bfeat[j0 + c * 4];
        acc2[c * 4 + 0] = b.x; acc2[c * 4 + 1] = b.y; acc2[c * 4 + 2] = b.z; acc2[c * 4 + 3] = b.w;
    }
    for (int kt = 0; kt < 8; ++kt) {
        float4 a = *(const float4*)&Xp[ln * XP_STRIDE + kt * 8];
        float4 b = *(const float4*)&Xp[ln * XP_STRIDE + kt * 8 + 4];
        float z8[8] = {a.x, a.y, a.z, a.w, b.x, b.y, b.z, b.w};
#pragma unroll
        for (int kk = 0; kk < 8; ++kk) {
            const float* wr = Wfeat + (size_t)(kt * 8 + kk) * FD + j0;
#pragma unroll
            for (int c = 0; c < 4; ++c) {
                float4 w = *(const float4*)(wr + c * 4);
                acc2[c * 4 + 0] += z8[kk] * w.x; acc2[c * 4 + 1] += z8[kk] * w.y;
                acc2[c * 4 + 2] += z8[kk] * w.z; acc2[c * 4 + 3] += z8[kk] * w.w;
            }
        }
    }
    if (n < N) {
        float* fo = feat_out + (size_t)n * FD + j0;
#pragma unroll
        for (int c = 0; c < 4; ++c)
            *(float4*)(fo + c * 4) = make_float4(lrelu(acc2[c * 4 + 0]), lrelu(acc2[c * 4 + 1]),
                                                 lrelu(acc2[c * 4 + 2]), lrelu(acc2[c * 4 + 3]));
    }
    __syncthreads();
    if (tid < 16 && lmax[tid] != 0u) atomicMax(&gmax_enc[tid], lmax[tid]);
}

// K4: per-graph  sum_e = sum exp(gate-gmax),  V = sum exp(gate-gmax)*feat
__global__ void k_pool(const float* __restrict__ gate, const float* __restrict__ feat,
                       const int* __restrict__ batch, const unsigned* __restrict__ gmax_enc,
                       float* __restrict__ sum_e, float* __restrict__ Vv, int N)
{
    int gid = blockIdx.x * blockDim.x + threadIdx.x;
    int wave = gid >> 6;
    int lane = threadIdx.x & 63;
    int nwaves = (gridDim.x * blockDim.x) >> 6;
    int chunk = (N + nwaves - 1) / nwaves;
    int n0 = wave * chunk;
    int n1 = min(N, n0 + chunk);
    if (n0 >= n1) return;
    int gcur = batch[n0];
    float gm = dec_f32(gmax_enc[gcur]);
    float accv = 0.f, acce = 0.f;
    for (int n = n0; n < n1; ++n) {
        int g = batch[n];
        if (g != gcur) {
            atomicAdd(&Vv[gcur * FD + lane], accv);
            if (lane == 0) atomicAdd(&sum_e[gcur], acce);
            gcur = g;
            gm = dec_f32(gmax_enc[g]);
            accv = 0.f; acce = 0.f;
        }
        float e = __expf(gate[n] - gm);
        accv += e * feat[(size_t)n * FD + lane];
        acce += e;
    }
    atomicAdd(&Vv[gcur * FD + lane], accv);
    if (lane == 0) atomicAdd(&sum_e[gcur], acce);
}

// K5: x_global' = lrelu([V/sum_e, x_global] @ Wt + bt) + x_global
__global__ void k_global(const float* __restrict__ xg_in, float* __restrict__ xg_out,
                         const float* __restrict__ Vv, const float* __restrict__ sum_e,
                         const float* __restrict__ Wt, const float* __restrict__ bt, int NG)
{
    __shared__ float xgn[FD], xgo[FD];
    int g = blockIdx.x, j = threadIdx.x;
    xgn[j] = Vv[g * FD + j] / sum_e[g];
    xgo[j] = xg_in[g * FD + j];
    __syncthreads();
    float acc = bt[j];
    for (int k = 0; k < FD; ++k) acc += xgn[k] * Wt[k * FD + j];
    for (int k = 0; k < FD; ++k) acc += xgo[k] * Wt[(FD + k) * FD + j];
    xg_out[g * FD + j] = lrelu(acc) + xgo[j];
}

extern "C" void kernel_launch(void* const* d_in, const int* in_sizes, int n_in,
                              void* d_out, int out_size, void* d_ws, size_t ws_size,
                              hipStream_t stream)
{
    const float* x0     = (const float*)d_in[0];
    const float* xg0    = (const float*)d_in[1];
    const int*   ei     = (const int*)d_in[3];
    const int*   batch  = (const int*)d_in[4];
    const float* Wm     = (const float*)d_in[6];
    const float* bm     = (const float*)d_in[7];
    const float* Wa     = (const float*)d_in[8];
    const float* ba     = (const float*)d_in[9];
    const float* Wgate  = (const float*)d_in[10];
    const float* bgate  = (const float*)d_in[11];
    const float* Wfeat  = (const float*)d_in[12];
    const float* bfeat  = (const float*)d_in[13];
    const float* Wt     = (const float*)d_in[14];
    const float* bt     = (const float*)d_in[15];

    const int N  = in_sizes[0] / FD;
    const int E  = in_sizes[3] / 2;
    const int NG = in_sizes[1] / FD;
    const int S  = in_sizes[6] / (FD * FD);

    const int* esrc_in = ei;       // edge_index[0]
    const int* edst_in = ei + E;   // edge_index[1]

    float* x_out  = (float*)d_out;
    float* xg_out = (float*)d_out + (size_t)N * FD;

    // ---- workspace layout ----
    char* ws = (char*)d_ws;
    const size_t rowB = (size_t)N * FD * 4;
    float* agg   = (float*)ws;
    float* p     = (float*)(ws + rowB);
    float* feat  = p;
    int*   esrc  = (int*)(ws + 2 * rowB);
    int*   off   = (int*)(ws + 2 * rowB + (size_t)E * 4);
    int*   endp  = off + N;
    int*   deg   = endp + N;
    float* gate  = (float*)deg;
    int*   bsums = deg + N;
    unsigned* gmax_enc = (unsigned*)(bsums + 1024);
    float* sum_e = (float*)(gmax_enc + 64);
    float* Vv    = sum_e + 64;

    const int nb_node = (N + 255) / 256;
    const int nb_edge = (E + 255) / 256;
    const int nb_scan = (N + SCAN_BS - 1) / SCAN_BS;
    const int nb_agg  = (N + 15) / 16;
    const int nb_q4   = ((N * 4) + 255) / 256;   // 4 threads/node kernels
    const int nb_n64  = (N + 63) / 64;           // k_node: 64 nodes/block

    // ---- preprocessing: CSR by dst ----
    hipMemsetAsync(deg, 0, (size_t)N * 4, stream);
    k_hist <<<nb_edge, 256, 0, stream>>>(edst_in, deg, E);
    k_scan1<<<nb_scan, SCAN_BS, 0, stream>>>(deg, off, bsums, N);
    k_scan2<<<1, SCAN_BS, 0, stream>>>(bsums, nb_scan);
    k_scan3<<<nb_node, 256, 0, stream>>>(off, bsums, endp, N);
    k_place<<<nb_edge, 256, 0, stream>>>(esrc_in, edst_in, endp, esrc, E);

    const float* x_in  = x0;
    const float* xg_in = xg0;

    for (int i = 0; i < S; ++i) {
        hipMemsetAsync(gmax_enc, 0, (64 + 64 + 1024) * 4, stream);
        k_proj<<<nb_q4, 256, 0, stream>>>(x_in, Wm + i * FD * FD, bm + i * FD, p, N);
        k_agg <<<nb_agg, 256, 0, stream>>>((const float4*)p, off, endp, esrc,
                                           (float4*)agg, N);
        k_node<<<nb_n64, 256, 0, stream>>>(x_in, x_out, xg_in, batch, agg,
                                           Wa + (size_t)i * 192 * FD, ba + i * FD,
                                           Wgate + i * FD, bgate + i,
                                           Wfeat + i * FD * FD, bfeat + i * FD,
                                           gate, feat, gmax_enc, N);
        k_pool<<<256, 256, 0, stream>>>(gate, feat, batch, gmax_enc, sum_e, Vv, N);
        k_global<<<NG, FD, 0, stream>>>(xg_in, xg_out, Vv, sum_e,
                                        Wt + (size_t)i * 2 * FD * FD, bt + i * FD, NG);
        x_in  = x_out;
        xg_in = xg_out;
    }
}

// Round 7
// 1241.261 us; speedup vs baseline: 2.2868x; 2.2868x over previous
//
#include <hip/hip_runtime.h>

#define FD 64           // feature dim D = A = G = 64
#define NSLOPE 0.01f
#define SCAN_BS 1024

__device__ __forceinline__ float lrelu(float v) { return v > 0.f ? v : NSLOPE * v; }

__device__ __forceinline__ unsigned enc_f32(float f) {
    unsigned u = __float_as_uint(f);
    return (u & 0x80000000u) ? ~u : (u | 0x80000000u);
}
__device__ __forceinline__ float dec_f32(unsigned u) {
    return (u & 0x80000000u) ? __uint_as_float(u & 0x7FFFFFFFu) : __uint_as_float(~u);
}

__device__ __forceinline__ float4 f4ma(float4 a, float s, float4 w) {
    a.x += s * w.x; a.y += s * w.y; a.z += s * w.z; a.w += s * w.w; return a;
}
#define LD4(p) (*(const float4*)(p))

// 16 named float4 accumulators (A0..A15) -> guaranteed VGPR residency
#define DECL_ACC float4 A0,A1,A2,A3,A4,A5,A6,A7,A8,A9,A10,A11,A12,A13,A14,A15;
#define INIT_ACC(b) { A0=LD4(b); A1=LD4((b)+4); A2=LD4((b)+8); A3=LD4((b)+12); \
    A4=LD4((b)+16); A5=LD4((b)+20); A6=LD4((b)+24); A7=LD4((b)+28); \
    A8=LD4((b)+32); A9=LD4((b)+36); A10=LD4((b)+40); A11=LD4((b)+44); \
    A12=LD4((b)+48); A13=LD4((b)+52); A14=LD4((b)+56); A15=LD4((b)+60); }
// one K-row: acc += s * W[row][0:64]  (wb lane-uniform -> scalar loads)
#define ROW(s, wb) { \
    A0=f4ma(A0,(s),LD4(wb)); A1=f4ma(A1,(s),LD4((wb)+4)); \
    A2=f4ma(A2,(s),LD4((wb)+8)); A3=f4ma(A3,(s),LD4((wb)+12)); \
    A4=f4ma(A4,(s),LD4((wb)+16)); A5=f4ma(A5,(s),LD4((wb)+20)); \
    A6=f4ma(A6,(s),LD4((wb)+24)); A7=f4ma(A7,(s),LD4((wb)+28)); \
    A8=f4ma(A8,(s),LD4((wb)+32)); A9=f4ma(A9,(s),LD4((wb)+36)); \
    A10=f4ma(A10,(s),LD4((wb)+40)); A11=f4ma(A11,(s),LD4((wb)+44)); \
    A12=f4ma(A12,(s),LD4((wb)+48)); A13=f4ma(A13,(s),LD4((wb)+52)); \
    A14=f4ma(A14,(s),LD4((wb)+56)); A15=f4ma(A15,(s),LD4((wb)+60)); }
// 8 K-rows starting at base_row, z values in za/zb
#define ROWS8(W, base_row, za, zb) { \
    const float* wb_ = (W) + (size_t)(base_row) * FD; \
    ROW((za).x, wb_);      ROW((za).y, wb_+FD);   ROW((za).z, wb_+2*FD); ROW((za).w, wb_+3*FD); \
    ROW((zb).x, wb_+4*FD); ROW((zb).y, wb_+5*FD); ROW((zb).z, wb_+6*FD); ROW((zb).w, wb_+7*FD); }

// ---------------- preprocessing: CSR by dst (every launch) ----------------

__global__ void k_hist(const int* __restrict__ dst, int* __restrict__ deg, int E)
{
    int e = blockIdx.x * blockDim.x + threadIdx.x;
    if (e < E) atomicAdd(&deg[dst[e]], 1);
}

__global__ void k_scan1(const int* __restrict__ deg, int* __restrict__ off,
                        int* __restrict__ bsums, int N)
{
    __shared__ int tmp[SCAN_BS];
    int t = threadIdx.x, b = blockIdx.x;
    int i = b * SCAN_BS + t;
    int v = (i < N) ? deg[i] : 0;
    tmp[t] = v;
    __syncthreads();
    for (int d = 1; d < SCAN_BS; d <<= 1) {
        int add = (t >= d) ? tmp[t - d] : 0;
        __syncthreads();
        tmp[t] += add;
        __syncthreads();
    }
    if (i < N) off[i] = tmp[t] - v;
    if (t == SCAN_BS - 1) bsums[b] = tmp[t];
}

__global__ void k_scan2(int* __restrict__ bsums, int nb)
{
    __shared__ int tmp[SCAN_BS];
    int t = threadIdx.x;
    int v = (t < nb) ? bsums[t] : 0;
    tmp[t] = v;
    __syncthreads();
    for (int d = 1; d < SCAN_BS; d <<= 1) {
        int add = (t >= d) ? tmp[t - d] : 0;
        __syncthreads();
        tmp[t] += add;
        __syncthreads();
    }
    if (t < nb) bsums[t] = tmp[t] - v;
}

__global__ void k_scan3(int* __restrict__ off, const int* __restrict__ bsums,
                        int* __restrict__ cursor, int N)
{
    int i = blockIdx.x * blockDim.x + threadIdx.x;
    if (i < N) {
        int o = off[i] + bsums[i >> 10];
        off[i] = o;
        cursor[i] = o;
    }
}

__global__ void k_place(const int* __restrict__ src, const int* __restrict__ dst,
                        int* __restrict__ cursor, int* __restrict__ esrc, int E)
{
    int e = blockIdx.x * blockDim.x + threadIdx.x;
    if (e >= E) return;
    int pos = atomicAdd(&cursor[dst[e]], 1);
    esrc[pos] = src[e];
}

// ---------------- per-step kernels ----------------

// K1: p = x @ Wm + bm.  1 thread/node, named-register accumulators.
__global__ void k_proj(const float* __restrict__ x, const float* __restrict__ Wm,
                       const float* __restrict__ bm, float* __restrict__ p, int N)
{
    int n = blockIdx.x * blockDim.x + threadIdx.x;
    if (n >= N) return;
    const float* xr = x + (size_t)n * FD;
    DECL_ACC
    INIT_ACC(bm)
    for (int kt = 0; kt < 8; ++kt) {
        float4 za = LD4(xr + kt * 8);
        float4 zb = LD4(xr + kt * 8 + 4);
        ROWS8(Wm, kt * 8, za, zb)
    }
    float* pr = p + (size_t)n * FD;
    *(float4*)(pr+ 0)=A0;  *(float4*)(pr+ 4)=A1;  *(float4*)(pr+ 8)=A2;  *(float4*)(pr+12)=A3;
    *(float4*)(pr+16)=A4;  *(float4*)(pr+20)=A5;  *(float4*)(pr+24)=A6;  *(float4*)(pr+28)=A7;
    *(float4*)(pr+32)=A8;  *(float4*)(pr+36)=A9;  *(float4*)(pr+40)=A10; *(float4*)(pr+44)=A11;
    *(float4*)(pr+48)=A12; *(float4*)(pr+52)=A13; *(float4*)(pr+56)=A14; *(float4*)(pr+60)=A15;
}

// K2: agg[n] = lrelu(max over in-edges of p[src]); empty -> 0.  16 thr/node.
__global__ void k_agg(const float4* __restrict__ p4, const int* __restrict__ off,
                      const int* __restrict__ endp, const int* __restrict__ esrc,
                      float4* __restrict__ agg4, int N)
{
    int tid = threadIdx.x;
    int q = tid & 15;
    int n = blockIdx.x * 16 + (tid >> 4);
    if (n >= N) return;
    int j0 = off[n], j1 = endp[n];
    float4 m = make_float4(-__builtin_inff(), -__builtin_inff(),
                           -__builtin_inff(), -__builtin_inff());
    int j = j0;
    for (; j + 1 < j1; j += 2) {
        int s0 = esrc[j], s1 = esrc[j + 1];
        float4 v0 = p4[(size_t)s0 * 16 + q];
        float4 v1 = p4[(size_t)s1 * 16 + q];
        m.x = fmaxf(m.x, v0.x); m.y = fmaxf(m.y, v0.y);
        m.z = fmaxf(m.z, v0.z); m.w = fmaxf(m.w, v0.w);
        m.x = fmaxf(m.x, v1.x); m.y = fmaxf(m.y, v1.y);
        m.z = fmaxf(m.z, v1.z); m.w = fmaxf(m.w, v1.w);
    }
    if (j < j1) {
        int s0 = esrc[j];
        float4 v0 = p4[(size_t)s0 * 16 + q];
        m.x = fmaxf(m.x, v0.x); m.y = fmaxf(m.y, v0.y);
        m.z = fmaxf(m.z, v0.z); m.w = fmaxf(m.w, v0.w);
    }
    float4 o;
    if (j0 == j1) o = make_float4(0.f, 0.f, 0.f, 0.f);
    else { o.x = lrelu(m.x); o.y = lrelu(m.y); o.z = lrelu(m.z); o.w = lrelu(m.w); }
    agg4[(size_t)n * 16 + q] = o;
}

// K3: 1 thread/node, named-register accumulators, lane-uniform weight rows.
// x' = lrelu([x,xg_b,agg] @ Wa + ba) + x ; gate + per-graph max ; feat = lrelu(x' @ Wfeat + bf)
__global__ void k_node(const float* __restrict__ x_in, float* __restrict__ x_out,
                       const float* __restrict__ xg, const int* __restrict__ batch,
                       const float* __restrict__ agg,
                       const float* __restrict__ Wa, const float* __restrict__ ba,
                       const float* __restrict__ Wgate, const float* __restrict__ bgate,
                       const float* __restrict__ Wfeat, const float* __restrict__ bfeat,
                       float* __restrict__ gate_out, float* __restrict__ feat_out,
                       unsigned* __restrict__ gmax_enc, int N)
{
    __shared__ unsigned lmax[16];
    int tid = threadIdx.x;
    if (tid < 16) lmax[tid] = 0u;
    __syncthreads();
    int n = blockIdx.x * blockDim.x + tid;
    if (n < N) {
        int g = batch[n];
        const float* xr  = x_in + (size_t)n * FD;
        const float* xgr = xg + (size_t)g * FD;
        const float* ar  = agg + (size_t)n * FD;
        DECL_ACC
        INIT_ACC(ba)
        // z segment 0: x  (rows 0..63)
        for (int kt = 0; kt < 8; ++kt) {
            float4 za = LD4(xr + kt * 8);
            float4 zb = LD4(xr + kt * 8 + 4);
            ROWS8(Wa, kt * 8, za, zb)
        }
        // z segment 1: x_global[batch]  (rows 64..127)
        for (int kt = 0; kt < 8; ++kt) {
            float4 za = LD4(xgr + kt * 8);
            float4 zb = LD4(xgr + kt * 8 + 4);
            ROWS8(Wa, 64 + kt * 8, za, zb)
        }
        // z segment 2: agg  (rows 128..191)
        for (int kt = 0; kt < 8; ++kt) {
            float4 za = LD4(ar + kt * 8);
            float4 zb = LD4(ar + kt * 8 + 4);
            ROWS8(Wa, 128 + kt * 8, za, zb)
        }
        // epilogue 1: x' = lrelu(acc) + x ; store ; gate dot
        float gv = bgate[0];
        float* xo = x_out + (size_t)n * FD;
#define XFIN(c, Ac) { float4 xv = LD4(xr + 4*(c)); float4 wg = LD4(Wgate + 4*(c)); \
        float4 v; v.x = lrelu(Ac.x) + xv.x; v.y = lrelu(Ac.y) + xv.y; \
        v.z = lrelu(Ac.z) + xv.z; v.w = lrelu(Ac.w) + xv.w; \
        *(float4*)(xo + 4*(c)) = v; \
        gv += v.x * wg.x + v.y * wg.y + v.z * wg.z + v.w * wg.w; }
        XFIN(0,A0) XFIN(1,A1) XFIN(2,A2) XFIN(3,A3)
        XFIN(4,A4) XFIN(5,A5) XFIN(6,A6) XFIN(7,A7)
        XFIN(8,A8) XFIN(9,A9) XFIN(10,A10) XFIN(11,A11)
        XFIN(12,A12) XFIN(13,A13) XFIN(14,A14) XFIN(15,A15)
#undef XFIN
        gate_out[n] = gv;
        atomicMax(&lmax[g], enc_f32(gv));
        // feat = lrelu(x' @ Wfeat + bfeat)  (re-read own x' row: L1-hot)
        INIT_ACC(bfeat)
        for (int kt = 0; kt < 8; ++kt) {
            float4 za = LD4(xo + kt * 8);
            float4 zb = LD4(xo + kt * 8 + 4);
            ROWS8(Wfeat, kt * 8, za, zb)
        }
        float* fo = feat_out + (size_t)n * FD;
#define FST(c, Ac) { float4 v; v.x = lrelu(Ac.x); v.y = lrelu(Ac.y); \
        v.z = lrelu(Ac.z); v.w = lrelu(Ac.w); *(float4*)(fo + 4*(c)) = v; }
        FST(0,A0) FST(1,A1) FST(2,A2) FST(3,A3)
        FST(4,A4) FST(5,A5) FST(6,A6) FST(7,A7)
        FST(8,A8) FST(9,A9) FST(10,A10) FST(11,A11)
        FST(12,A12) FST(13,A13) FST(14,A14) FST(15,A15)
#undef FST
    }
    __syncthreads();
    if (tid < 16 && lmax[tid] != 0u) atomicMax(&gmax_enc[tid], lmax[tid]);
}

// K4: per-graph  sum_e = sum exp(gate-gmax),  V = sum exp(gate-gmax)*feat
__global__ void k_pool(const float* __restrict__ gate, const float* __restrict__ feat,
                       const int* __restrict__ batch, const unsigned* __restrict__ gmax_enc,
                       float* __restrict__ sum_e, float* __restrict__ Vv, int N)
{
    int gid = blockIdx.x * blockDim.x + threadIdx.x;
    int wave = gid >> 6;
    int lane = threadIdx.x & 63;
    int nwaves = (gridDim.x * blockDim.x) >> 6;
    int chunk = (N + nwaves - 1) / nwaves;
    int n0 = wave * chunk;
    int n1 = min(N, n0 + chunk);
    if (n0 >= n1) return;
    int gcur = batch[n0];
    float gm = dec_f32(gmax_enc[gcur]);
    float accv = 0.f, acce = 0.f;
    for (int n = n0; n < n1; ++n) {
        int g = batch[n];
        if (g != gcur) {
            atomicAdd(&Vv[gcur * FD + lane], accv);
            if (lane == 0) atomicAdd(&sum_e[gcur], acce);
            gcur = g;
            gm = dec_f32(gmax_enc[g]);
            accv = 0.f; acce = 0.f;
        }
        float e = __expf(gate[n] - gm);
        accv += e * feat[(size_t)n * FD + lane];
        acce += e;
    }
    atomicAdd(&Vv[gcur * FD + lane], accv);
    if (lane == 0) atomicAdd(&sum_e[gcur], acce);
}

// K5: x_global' = lrelu([V/sum_e, x_global] @ Wt + bt) + x_global
__global__ void k_global(const float* __restrict__ xg_in, float* __restrict__ xg_out,
                         const float* __restrict__ Vv, const float* __restrict__ sum_e,
                         const float* __restrict__ Wt, const float* __restrict__ bt, int NG)
{
    __shared__ float xgn[FD], xgo[FD];
    int g = blockIdx.x, j = threadIdx.x;
    xgn[j] = Vv[g * FD + j] / sum_e[g];
    xgo[j] = xg_in[g * FD + j];
    __syncthreads();
    float acc = bt[j];
    for (int k = 0; k < FD; ++k) acc += xgn[k] * Wt[k * FD + j];
    for (int k = 0; k < FD; ++k) acc += xgo[k] * Wt[(FD + k) * FD + j];
    xg_out[g * FD + j] = lrelu(acc) + xgo[j];
}

extern "C" void kernel_launch(void* const* d_in, const int* in_sizes, int n_in,
                              void* d_out, int out_size, void* d_ws, size_t ws_size,
                              hipStream_t stream)
{
    const float* x0     = (const float*)d_in[0];
    const float* xg0    = (const float*)d_in[1];
    const int*   ei     = (const int*)d_in[3];
    const int*   batch  = (const int*)d_in[4];
    const float* Wm     = (const float*)d_in[6];
    const float* bm     = (const float*)d_in[7];
    const float* Wa     = (const float*)d_in[8];
    const float* ba     = (const float*)d_in[9];
    const float* Wgate  = (const float*)d_in[10];
    const float* bgate  = (const float*)d_in[11];
    const float* Wfeat  = (const float*)d_in[12];
    const float* bfeat  = (const float*)d_in[13];
    const float* Wt     = (const float*)d_in[14];
    const float* bt     = (const float*)d_in[15];

    const int N  = in_sizes[0] / FD;
    const int E  = in_sizes[3] / 2;
    const int NG = in_sizes[1] / FD;
    const int S  = in_sizes[6] / (FD * FD);

    const int* esrc_in = ei;       // edge_index[0]
    const int* edst_in = ei + E;   // edge_index[1]

    float* x_out  = (float*)d_out;
    float* xg_out = (float*)d_out + (size_t)N * FD;

    // ---- workspace layout ----
    char* ws = (char*)d_ws;
    const size_t rowB = (size_t)N * FD * 4;
    float* agg   = (float*)ws;
    float* p     = (float*)(ws + rowB);
    float* feat  = p;
    int*   esrc  = (int*)(ws + 2 * rowB);
    int*   off   = (int*)(ws + 2 * rowB + (size_t)E * 4);
    int*   endp  = off + N;
    int*   deg   = endp + N;
    float* gate  = (float*)deg;
    int*   bsums = deg + N;
    unsigned* gmax_enc = (unsigned*)(bsums + 1024);
    float* sum_e = (float*)(gmax_enc + 64);
    float* Vv    = sum_e + 64;

    const int nb_node = (N + 255) / 256;
    const int nb_edge = (E + 255) / 256;
    const int nb_scan = (N + SCAN_BS - 1) / SCAN_BS;
    const int nb_agg  = (N + 15) / 16;

    // ---- preprocessing: CSR by dst ----
    hipMemsetAsync(deg, 0, (size_t)N * 4, stream);
    k_hist <<<nb_edge, 256, 0, stream>>>(edst_in, deg, E);
    k_scan1<<<nb_scan, SCAN_BS, 0, stream>>>(deg, off, bsums, N);
    k_scan2<<<1, SCAN_BS, 0, stream>>>(bsums, nb_scan);
    k_scan3<<<nb_node, 256, 0, stream>>>(off, bsums, endp, N);
    k_place<<<nb_edge, 256, 0, stream>>>(esrc_in, edst_in, endp, esrc, E);

    const float* x_in  = x0;
    const float* xg_in = xg0;

    for (int i = 0; i < S; ++i) {
        hipMemsetAsync(gmax_enc, 0, (64 + 64 + 1024) * 4, stream);
        k_proj<<<nb_node, 256, 0, stream>>>(x_in, Wm + i * FD * FD, bm + i * FD, p, N);
        k_agg <<<nb_agg, 256, 0, stream>>>((const float4*)p, off, endp, esrc,
                                           (float4*)agg, N);
        k_node<<<nb_node, 256, 0, stream>>>(x_in, x_out, xg_in, batch, agg,
                                            Wa + (size_t)i * 192 * FD, ba + i * FD,
                                            Wgate + i * FD, bgate + i,
                                            Wfeat + i * FD * FD, bfeat + i * FD,
                                            gate, feat, gmax_enc, N);
        k_pool<<<256, 256, 0, stream>>>(gate, feat, batch, gmax_enc, sum_e, Vv, N);
        k_global<<<NG, FD, 0, stream>>>(xg_in, xg_out, Vv, sum_e,
                                        Wt + (size_t)i * 2 * FD * FD, bt + i * FD, NG);
        x_in  = x_out;
        xg_in = xg_out;
    }
}